// Round 9
// baseline (1622.087 us; speedup 1.0000x reference)
//
#include <hip/hip_runtime.h>
#include <hip/hip_bf16.h>

typedef __attribute__((ext_vector_type(8))) short short8;
typedef __attribute__((ext_vector_type(4))) float f32x4;
typedef unsigned short u16;

__device__ __forceinline__ u16 f2b(float f) {
    unsigned int u = __builtin_bit_cast(unsigned int, f);
    u = u + 0x7fffu + ((u >> 16) & 1u);
    return (u16)(u >> 16);
}

// epilogue modes (template parameter)
#define EPI_F32      0   // outF = acc + bias0
#define EPI_RESID_XB 3   // outF = acc+bias0+Rsd, outB = bf16(same)
#define EPI_GELU     4   // outB = bf16(gelu(acc + bias0))
#define EPI_KV       7   // 2-way split: K(outB), V-transposed(outV); batched by bz
#define EPI_ATOMIC   9   // atomicAdd(outF, acc) (+bias0 when bz==0), split-K

// ---------------------------------------------------------------------------
// bf16 MFMA GEMM: C = A(M,K) @ Bt(N,K)^T, f32 accumulate, fused epilogue EPI.
// BM in {32,64,128}, BN in {64,128}, BK in {32,64}, 256 threads.
// BM=32 uses a 2x2 wave layout (WM=16, WN=32) for 1024+ block grids.
// 2-phase double-buffered K-loop, global_load_lds width=16, source-side
// XOR swizzle, XCD-aware bijective block swizzle (needs nwg % 8 == 0).
// ---------------------------------------------------------------------------
template<int BM, int BN, int BK, int EPI>
__global__ __launch_bounds__(256, 2) void gemm_bf16(
    const u16* __restrict__ A, long aStride, int lda,
    const u16* __restrict__ B, long bStride, int ldb,
    int M, int N, int K,
    const float* __restrict__ bias0, const float* __restrict__ bias1,
    int biasStride,
    const float* __restrict__ Rsd,
    float* __restrict__ outF, u16* __restrict__ outB,
    u16* __restrict__ outV, long outStride, int ldc)
{
    constexpr int WCOLS = (BM == 32) ? 2 : (BN / 64);
    constexpr int WROWS = 4 / WCOLS;
    constexpr int WM = BM / WROWS;           // rows per wave (>=16)
    constexpr int WN = BN / WCOLS;           // cols per wave
    constexpr int MF = WM / 16;
    constexpr int NF = WN / 16;
    constexpr int GR = BK / 8;               // 16B units per row
    constexpr int AUNITS = BM * GR;
    constexpr int TOTU = (BM + BN) * GR;
    constexpr int UPT = (TOTU + 255) / 256;
    constexpr int BUFE = (BM + BN) * BK;     // u16 per LDS buffer

    __shared__ __align__(16) u16 smem[2 * BUFE];

    const int tid = threadIdx.x;
    const int wave = tid >> 6, lane = tid & 63;
    const int wm = wave / WCOLS, wn = wave % WCOLS;

    // XCD-aware bijective swizzle (chunked)
    const int nwg = gridDim.x * gridDim.y;
    const int bl = blockIdx.y * gridDim.x + blockIdx.x;
    const int wsw = (bl & 7) * (nwg >> 3) + (bl >> 3);
    const int bxs = wsw % gridDim.x, bys = wsw / gridDim.x;

    const int tm = bys * BM, tn = bxs * BN;
    const int bz = blockIdx.z;

    const size_t aOff = (size_t)bz * (size_t)aStride;
    const size_t bOff = (size_t)bz * (size_t)bStride;

    const int lr = lane & 15, kg = lane >> 4;

    auto stage = [&](int buf, int k0) {
#pragma unroll
        for (int i = 0; i < UPT; i++) {
            int u = tid + i * 256;
            if (u < TOTU) {
                u16* dst = smem + buf * BUFE + u * 8;
                bool isA = u < AUNITS;
                int v = isA ? u : u - AUNITS;
                int row, kloc;
                if constexpr (BK == 64) {
                    row = v >> 3;
                    int hh = (v >> 2) & 1, g = v & 3;
                    kloc = ((hh ^ (row & 1)) << 5) + ((g ^ ((row >> 1) & 3)) << 3);
                } else {
                    row = v >> 2;
                    int g = v & 3;
                    kloc = (g ^ ((row >> 1) & 3)) << 3;
                }
                const u16* src = isA
                    ? A + aOff + (size_t)(tm + row) * lda + k0 + kloc
                    : B + bOff + (size_t)(tn + row) * ldb + k0 + kloc;
                __builtin_amdgcn_global_load_lds(src, dst, 16, 0, 0);
            }
        }
    };

    auto ldsOff = [&](int row, int kk) -> int {
        if constexpr (BK == 64)
            return row * 64 + (((kk ^ (row & 1)) * 4 + (kg ^ ((row >> 1) & 3))) * 8);
        else
            return row * 32 + ((kg ^ ((row >> 1) & 3)) * 8);
    };

    f32x4 acc[MF][NF];
#pragma unroll
    for (int m = 0; m < MF; m++)
#pragma unroll
        for (int n = 0; n < NF; n++) acc[m][n] = (f32x4)(0.f);

    const int NT = K / BK;
    stage(0, 0);
    __syncthreads();

    for (int t = 0; t < NT; t++) {
        const int cur = t & 1;
        if (t + 1 < NT) stage(cur ^ 1, (t + 1) * BK);

        const u16* As = smem + cur * BUFE;
        const u16* Bs = As + BM * BK;
#pragma unroll
        for (int kk = 0; kk < BK / 32; kk++) {
            short8 af[MF], bfr[NF];
#pragma unroll
            for (int m = 0; m < MF; m++) {
                int row = wm * WM + m * 16 + lr;
                af[m] = *(const short8*)&As[ldsOff(row, kk)];
            }
#pragma unroll
            for (int n = 0; n < NF; n++) {
                int row = wn * WN + n * 16 + lr;
                bfr[n] = *(const short8*)&Bs[ldsOff(row, kk)];
            }
#pragma unroll
            for (int m = 0; m < MF; m++)
#pragma unroll
                for (int n = 0; n < NF; n++)
                    acc[m][n] = __builtin_amdgcn_mfma_f32_16x16x32_bf16(
                        af[m], bfr[n], acc[m][n], 0, 0, 0);
        }
        __syncthreads();   // drains prefetch (vmcnt 0) + joins waves
    }

    if constexpr (EPI == EPI_KV) {
        if (tn < 2048) {
            // ---- K half: coalesced direct stores ----
#pragma unroll
            for (int m = 0; m < MF; m++)
#pragma unroll
                for (int n = 0; n < NF; n++)
#pragma unroll
                    for (int e = 0; e < 4; e++) {
                        int r = tm + wm * WM + m * 16 + kg * 4 + e;
                        int c = tn + wn * WN + n * 16 + lr;
                        float t = acc[m][n][e] + bias0[bz * biasStride + c];
                        outB[(size_t)bz * outStride + (size_t)r * 2048 + c] = f2b(t);
                    }
        } else {
            // ---- V half: transpose via LDS, coalesced uint4 stores ----
            const int ccb = tn - 2048;             // multiple of 128
            const int bidx = tm >> 8;              // batch index
            const int hh = ccb >> 8;               // head
            u16* vls = smem;                       // [128 d][136 pad] u16
#pragma unroll
            for (int m = 0; m < MF; m++)
#pragma unroll
                for (int n = 0; n < NF; n++)
#pragma unroll
                    for (int e = 0; e < 4; e++) {
                        int rl = wm * WM + m * 16 + kg * 4 + e;   // local tok
                        int cl = wn * WN + n * 16 + lr;           // local d
                        float t = acc[m][n][e] + bias1[bz * biasStride + ccb + cl];
                        vls[cl * 136 + rl] = f2b(t);
                    }
            __syncthreads();
            const int dloc = tid >> 1;
            const int thalf = (tid & 1) * 64;
            const int dglob = (ccb & 255) + dloc;
            u16* dst = outV + (size_t)bz * outStride +
                       (size_t)(bidx * 8 + hh) * 65536 +
                       (size_t)dglob * 256 + (tm & 255) + thalf;
            const u16* srcl = vls + dloc * 136 + thalf;
#pragma unroll
            for (int k = 0; k < 8; k++)
                *(uint4*)(dst + k * 8) = *(const uint4*)(srcl + k * 8);
        }
        return;
    }

    // generic epilogue: D row=(lane>>4)*4+e, col=lane&15
#pragma unroll
    for (int m = 0; m < MF; m++) {
#pragma unroll
        for (int n = 0; n < NF; n++) {
#pragma unroll
            for (int e = 0; e < 4; e++) {
                int r = tm + wm * WM + m * 16 + (lane >> 4) * 4 + e;
                int c = tn + wn * WN + n * 16 + (lane & 15);
                float v = acc[m][n][e];
                if constexpr (EPI == EPI_F32) {
                    outF[(size_t)r * ldc + c] = v + bias0[c];
                } else if constexpr (EPI == EPI_RESID_XB) {
                    float t = v + bias0[c] + Rsd[(size_t)r * ldc + c];
                    outF[(size_t)r * ldc + c] = t;
                    outB[(size_t)r * ldc + c] = f2b(t);
                } else if constexpr (EPI == EPI_GELU) {
                    float t = v + bias0[c];
                    t = 0.5f * t * (1.f + erff(t * 0.70710678118654752f));
                    outB[(size_t)r * ldc + c] = f2b(t);
                } else if constexpr (EPI == EPI_ATOMIC) {
                    float t = v;
                    if (bz == 0) t += bias0[c];
                    atomicAdd(&outF[(size_t)r * ldc + c], t);
                }
            }
        }
    }
}

// ---------------------------------------------------------------------------
// Fused attention with Q-projection, QBLK=32 rows per block (grid 8 x 128,
// 3 blocks/CU resident). Phases: 0 Q-proj, 1 QK^T, 2 softmax(+1), 3 P->LDS,
// 4 PV. XCD swizzle + s_setprio around MFMA clusters.
// ---------------------------------------------------------------------------
template<bool MASKED>
__global__ __launch_bounds__(256, 2) void attn_kernel(
    const u16* __restrict__ Aq, const u16* __restrict__ WqT,
    const float* __restrict__ bq,
    const u16* __restrict__ K, const u16* __restrict__ Vt,
    const int* __restrict__ adj, u16* __restrict__ O)
{
    __shared__ __align__(16) u16 Ps[32 * 256];       // Q tile then P tile (16 KB)
    __shared__ __align__(16) u16 Ks[2 * 256 * 32];   // B double buffer (32 KB)
    __shared__ __align__(16) u16 Aql[2 * 32 * 32];   // phase-0 A dbuf (4 KB)
    __shared__ float red1[32 * 4];
    __shared__ float red2[32 * 4];

    const int tid = threadIdx.x;
    const int w = tid >> 6, lane = tid & 63;
    const int lr = lane & 15, kg = lane >> 4;

    // XCD swizzle: 8 qt-blocks of a bh colocate
    const int nwg = gridDim.x * gridDim.y;
    const int bl = blockIdx.y * gridDim.x + blockIdx.x;
    const int wsw = (bl & 7) * (nwg >> 3) + (bl >> 3);
    const int qt = wsw % gridDim.x, bh = wsw / gridDim.x;

    const int b = bh >> 3, h = bh & 7;
    const size_t qkBase = (size_t)b * 256 * 2048 + h * 256;

    auto stageA0 = [&](int buf, int k0) {
        if (tid < 128) {                   // 32 rows x 4 groups
            int row = tid >> 2, g = tid & 3;
            int gs = g ^ ((row >> 1) & 3);
            const u16* src = Aq + (size_t)(b * 256 + qt * 32 + row) * 512 + k0 + gs * 8;
            __builtin_amdgcn_global_load_lds(src, Aql + buf * 1024 + tid * 8, 16, 0, 0);
        }
    };
    auto stageB0 = [&](int buf, int k0) {
#pragma unroll
        for (int i = 0; i < 4; i++) {
            int u = tid + i * 256;
            int row = u >> 2, g = u & 3;
            int gs = g ^ ((row >> 1) & 3);
            const u16* src = WqT + (size_t)(h * 256 + row) * 512 + k0 + gs * 8;
            __builtin_amdgcn_global_load_lds(src, Ks + buf * 8192 + u * 8, 16, 0, 0);
        }
    };
    auto stageK = [&](int buf, int dk) {
#pragma unroll
        for (int i = 0; i < 4; i++) {
            int u = tid + i * 256;
            int row = u >> 2, g = u & 3;
            int gs = g ^ ((row >> 1) & 3);
            const u16* src = K + qkBase + (size_t)row * 2048 + dk * 32 + gs * 8;
            __builtin_amdgcn_global_load_lds(src, Ks + buf * 8192 + u * 8, 16, 0, 0);
        }
    };
    auto stageV = [&](int buf, int kt) {
#pragma unroll
        for (int i = 0; i < 4; i++) {
            int u = tid + i * 256;
            int row = u >> 2, g = u & 3;   // row = d
            int gs = g ^ ((row >> 1) & 3);
            const u16* src = Vt + (size_t)bh * 65536 + (size_t)row * 256 + kt * 32 + gs * 8;
            __builtin_amdgcn_global_load_lds(src, Ks + buf * 8192 + u * 8, 16, 0, 0);
        }
    };

    // ---- phase 0: Q = Aq @ WqT_head + bq  (K=512, 16 steps of 32) ----
    {
        f32x4 qacc[2][4];
#pragma unroll
        for (int m = 0; m < 2; m++)
#pragma unroll
            for (int n = 0; n < 4; n++) qacc[m][n] = (f32x4)(0.f);

        stageA0(0, 0);
        stageB0(0, 0);
        __syncthreads();
        for (int t = 0; t < 16; t++) {
            const int cur = t & 1;
            if (t < 15) { stageA0(cur ^ 1, (t + 1) * 32); stageB0(cur ^ 1, (t + 1) * 32); }
            short8 af[2], bfr[4];
#pragma unroll
            for (int m = 0; m < 2; m++) {
                int row = m * 16 + lr;
                af[m] = *(const short8*)&Aql[cur * 1024 + row * 32 + ((kg ^ ((row >> 1) & 3)) * 8)];
            }
#pragma unroll
            for (int n = 0; n < 4; n++) {
                int row = w * 64 + n * 16 + lr;
                bfr[n] = *(const short8*)&Ks[cur * 8192 + row * 32 + ((kg ^ ((row >> 1) & 3)) * 8)];
            }
            __builtin_amdgcn_s_setprio(1);
#pragma unroll
            for (int m = 0; m < 2; m++)
#pragma unroll
                for (int n = 0; n < 4; n++)
                    qacc[m][n] = __builtin_amdgcn_mfma_f32_16x16x32_bf16(
                        af[m], bfr[n], qacc[m][n], 0, 0, 0);
            __builtin_amdgcn_s_setprio(0);
            __syncthreads();
        }
        // write Q tile to Ps (bf16, swizzled for phase-1 A reads)
#pragma unroll
        for (int m = 0; m < 2; m++)
#pragma unroll
            for (int n = 0; n < 4; n++)
#pragma unroll
                for (int e = 0; e < 4; e++) {
                    int q = m * 16 + kg * 4 + e;
                    int d = w * 64 + n * 16 + lr;
                    float t = qacc[m][n][e] + bq[h * 256 + d];
                    Ps[q * 256 + (((d >> 3) ^ (q & 7)) * 8) + (d & 7)] = f2b(t);
                }
    }
    __syncthreads();

    f32x4 sacc[2][4];
#pragma unroll
    for (int m = 0; m < 2; m++)
#pragma unroll
        for (int n = 0; n < 4; n++) sacc[m][n] = (f32x4)(0.f);

    // ---- phase 1: S = Q K^T (contraction over d, 8 steps of 32) ----
    stageK(0, 0);
    __syncthreads();
    for (int dk = 0; dk < 8; dk++) {
        const int cur = dk & 1;
        if (dk < 7) stageK(cur ^ 1, dk + 1);
        short8 af[2], bfr[4];
#pragma unroll
        for (int m = 0; m < 2; m++) {
            int row = m * 16 + lr;
            af[m] = *(const short8*)&Ps[row * 256 + (((dk * 4 + kg) ^ (row & 7)) * 8)];
        }
#pragma unroll
        for (int n = 0; n < 4; n++) {
            int row = w * 64 + n * 16 + lr;
            bfr[n] = *(const short8*)&Ks[cur * 8192 + row * 32 + ((kg ^ ((row >> 1) & 3)) * 8)];
        }
        __builtin_amdgcn_s_setprio(1);
#pragma unroll
        for (int m = 0; m < 2; m++)
#pragma unroll
            for (int n = 0; n < 4; n++)
                sacc[m][n] = __builtin_amdgcn_mfma_f32_16x16x32_bf16(
                    af[m], bfr[n], sacc[m][n], 0, 0, 0);
        __builtin_amdgcn_s_setprio(0);
        __syncthreads();
    }

    // prefetch V tile 0 into Ks buf0 (overlaps softmax)
    stageV(0, 0);

    // ---- phase 2: scale + mask + softmax(+1 denom) ----
#pragma unroll
    for (int m = 0; m < 2; m++)
#pragma unroll
        for (int n = 0; n < 4; n++)
#pragma unroll
            for (int e = 0; e < 4; e++) {
                float t = sacc[m][n][e] * 0.0625f;
                if (MASKED) {
                    int q = qt * 32 + m * 16 + kg * 4 + e;
                    int k = w * 64 + n * 16 + lr;
                    int a_ = adj[((size_t)b * 256 + q) * 256 + k];
                    t += (1.f - (float)a_) * -1.0e6f;
                }
                sacc[m][n][e] = t;
            }

    float mx[2][4];
#pragma unroll
    for (int m = 0; m < 2; m++)
#pragma unroll
        for (int e = 0; e < 4; e++) {
            float v = sacc[m][0][e];
#pragma unroll
            for (int n = 1; n < 4; n++) v = fmaxf(v, sacc[m][n][e]);
#pragma unroll
            for (int off = 1; off < 16; off <<= 1) v = fmaxf(v, __shfl_xor(v, off));
            mx[m][e] = v;
        }
    if (lr == 0) {
#pragma unroll
        for (int m = 0; m < 2; m++)
#pragma unroll
            for (int e = 0; e < 4; e++)
                red1[(m * 16 + kg * 4 + e) * 4 + w] = mx[m][e];
    }
    __syncthreads();

    float inv[2][4];
    float sum[2][4];
#pragma unroll
    for (int m = 0; m < 2; m++)
#pragma unroll
        for (int e = 0; e < 4; e++) {
            int r = m * 16 + kg * 4 + e;
            float gm = fmaxf(fmaxf(red1[r * 4 + 0], red1[r * 4 + 1]),
                             fmaxf(red1[r * 4 + 2], red1[r * 4 + 3]));
            float s = 0.f;
#pragma unroll
            for (int n = 0; n < 4; n++) {
                float ev = __expf(sacc[m][n][e] - gm);
                sacc[m][n][e] = ev;
                s += ev;
            }
            sum[m][e] = s;
        }
#pragma unroll
    for (int m = 0; m < 2; m++)
#pragma unroll
        for (int e = 0; e < 4; e++) {
            float s = sum[m][e];
#pragma unroll
            for (int off = 1; off < 16; off <<= 1) s += __shfl_xor(s, off);
            sum[m][e] = s;
        }
    if (lr == 0) {
#pragma unroll
        for (int m = 0; m < 2; m++)
#pragma unroll
            for (int e = 0; e < 4; e++)
                red2[(m * 16 + kg * 4 + e) * 4 + w] = sum[m][e];
    }
    __syncthreads();
#pragma unroll
    for (int m = 0; m < 2; m++)
#pragma unroll
        for (int e = 0; e < 4; e++) {
            int r = m * 16 + kg * 4 + e;
            float gs = red2[r * 4 + 0] + red2[r * 4 + 1] +
                       red2[r * 4 + 2] + red2[r * 4 + 3];
            inv[m][e] = 1.f / (1.f + gs);
        }

    // ---- phase 3: P -> LDS (bf16, overwrites Q tile) ----
#pragma unroll
    for (int m = 0; m < 2; m++)
#pragma unroll
        for (int n = 0; n < 4; n++)
#pragma unroll
            for (int e = 0; e < 4; e++) {
                int q = m * 16 + kg * 4 + e;
                int k = w * 64 + n * 16 + lr;
                float pv = sacc[m][n][e] * inv[m][e];
                Ps[q * 256 + (((k >> 3) ^ (q & 7)) * 8) + (k & 7)] = f2b(pv);
            }
    __syncthreads();   // P visible; V tile 0 drained

    // ---- phase 4: O = P V (contraction over k, 8 steps of 32) ----
    f32x4 oacc[2][4];
#pragma unroll
    for (int m = 0; m < 2; m++)
#pragma unroll
        for (int n = 0; n < 4; n++) oacc[m][n] = (f32x4)(0.f);

    for (int kt = 0; kt < 8; kt++) {
        const int cur = kt & 1;
        if (kt < 7) stageV(cur ^ 1, kt + 1);
        short8 af[2], bfr[4];
#pragma unroll
        for (int m = 0; m < 2; m++) {
            int q = m * 16 + lr;
            af[m] = *(const short8*)&Ps[q * 256 + (((kt * 4 + kg) ^ (q & 7)) * 8)];
        }
#pragma unroll
        for (int n = 0; n < 4; n++) {
            int row = w * 64 + n * 16 + lr;
            bfr[n] = *(const short8*)&Ks[cur * 8192 + row * 32 + ((kg ^ ((row >> 1) & 3)) * 8)];
        }
        __builtin_amdgcn_s_setprio(1);
#pragma unroll
        for (int m = 0; m < 2; m++)
#pragma unroll
            for (int n = 0; n < 4; n++)
                oacc[m][n] = __builtin_amdgcn_mfma_f32_16x16x32_bf16(
                    af[m], bfr[n], oacc[m][n], 0, 0, 0);
        __builtin_amdgcn_s_setprio(0);
        __syncthreads();
    }

    // ---- epilogue: O[tok][h*256+d] ----
#pragma unroll
    for (int m = 0; m < 2; m++)
#pragma unroll
        for (int n = 0; n < 4; n++)
#pragma unroll
            for (int e = 0; e < 4; e++) {
                int q = qt * 32 + m * 16 + kg * 4 + e;
                int d = w * 64 + n * 16 + lr;
                O[(size_t)(b * 256 + q) * 2048 + h * 256 + d] = f2b(oacc[m][n][e]);
            }
}

// ---------------------------------------------------------------------------
// Transpose+convert: src f32 [R][C] -> dst bf16 [C][R].
// 128-row x 64-col tiles: 8 float4 loads + 8 uint2 stores per thread.
// ---------------------------------------------------------------------------
__global__ __launch_bounds__(256) void transpose_kernel(
    const float* p0, const float* p1, const float* p2,
    const float* p3, const float* p4, const float* p5,
    int nsrc, long srcLayerStride, int R, int C,
    u16* __restrict__ out, long dstMatStride, long dstLayerStride)
{
    const int mat = blockIdx.z % nsrc, layer = blockIdx.z / nsrc;
    const float* W;
    switch (mat) {
    default: W = p0; break;
    case 1: W = p1; break;
    case 2: W = p2; break;
    case 3: W = p3; break;
    case 4: W = p4; break;
    case 5: W = p5; break;
    }
    W += (size_t)layer * srcLayerStride;
    u16* o = out + (size_t)layer * dstLayerStride + (size_t)mat * dstMatStride;
    __shared__ float t[128][65];
    const int tid = threadIdx.x;
    const int rBase = blockIdx.y * 128, cBase = blockIdx.x * 64;
#pragma unroll
    for (int i = 0; i < 8; i++) {
        int idx = tid + i * 256;
        int rr = idx >> 4, cc4 = (idx & 15) * 4;
        if (rBase + rr < R) {
            float4 v = *(const float4*)&W[(size_t)(rBase + rr) * C + cBase + cc4];
            t[rr][cc4] = v.x; t[rr][cc4 + 1] = v.y;
            t[rr][cc4 + 2] = v.z; t[rr][cc4 + 3] = v.w;
        }
    }
    __syncthreads();
#pragma unroll
    for (int i = 0; i < 8; i++) {
        int idx = tid + i * 256;
        int cc = idx >> 5, rr4 = (idx & 31) * 4;
        if (rBase + rr4 < R) {
            uint2 pk;
            pk.x = (unsigned)f2b(t[rr4][cc]) | ((unsigned)f2b(t[rr4 + 1][cc]) << 16);
            pk.y = (unsigned)f2b(t[rr4 + 2][cc]) | ((unsigned)f2b(t[rr4 + 3][cc]) << 16);
            *(uint2*)&o[(size_t)(cBase + cc) * R + rBase + rr4] = pk;
        }
    }
}

// ---------------------------------------------------------------------------
// LayerNorm rows of 512, f32 in -> bf16 out. One wave per row.
// ---------------------------------------------------------------------------
__global__ __launch_bounds__(256) void ln_kernel(
    const float* __restrict__ X, const float* __restrict__ g,
    const float* __restrict__ b, u16* __restrict__ Y)
{
    const int wave = threadIdx.x >> 6, lane = threadIdx.x & 63;
    const size_t row = (size_t)blockIdx.x * 4 + wave;
    const float* xr = X + row * 512;
    float4 v0 = *reinterpret_cast<const float4*>(xr + lane * 8);
    float4 v1 = *reinterpret_cast<const float4*>(xr + lane * 8 + 4);
    float s = v0.x + v0.y + v0.z + v0.w + v1.x + v1.y + v1.z + v1.w;
    float ss = v0.x * v0.x + v0.y * v0.y + v0.z * v0.z + v0.w * v0.w +
               v1.x * v1.x + v1.y * v1.y + v1.z * v1.z + v1.w * v1.w;
#pragma unroll
    for (int off = 32; off; off >>= 1) {
        s += __shfl_xor(s, off);
        ss += __shfl_xor(ss, off);
    }
    float mu = s * (1.0f / 512.0f);
    float var = ss * (1.0f / 512.0f) - mu * mu;
    float rs = rsqrtf(var + 1e-5f);
    float4 g0 = *reinterpret_cast<const float4*>(g + lane * 8);
    float4 g1 = *reinterpret_cast<const float4*>(g + lane * 8 + 4);
    float4 b0 = *reinterpret_cast<const float4*>(b + lane * 8);
    float4 b1 = *reinterpret_cast<const float4*>(b + lane * 8 + 4);
    float o0 = (v0.x - mu) * rs * g0.x + b0.x;
    float o1 = (v0.y - mu) * rs * g0.y + b0.y;
    float o2 = (v0.z - mu) * rs * g0.z + b0.z;
    float o3 = (v0.w - mu) * rs * g0.w + b0.w;
    float o4 = (v1.x - mu) * rs * g1.x + b1.x;
    float o5 = (v1.y - mu) * rs * g1.y + b1.y;
    float o6 = (v1.z - mu) * rs * g1.z + b1.z;
    float o7 = (v1.w - mu) * rs * g1.w + b1.w;
    uint4 pk;
    pk.x = (unsigned)f2b(o0) | ((unsigned)f2b(o1) << 16);
    pk.y = (unsigned)f2b(o2) | ((unsigned)f2b(o3) << 16);
    pk.z = (unsigned)f2b(o4) | ((unsigned)f2b(o5) << 16);
    pk.w = (unsigned)f2b(o6) | ((unsigned)f2b(o7) << 16);
    *reinterpret_cast<uint4*>(Y + row * 512 + lane * 8) = pk;
}

// ---------------------------------------------------------------------------
// Embedding gather -> bf16 (2 elems/thread)
// ---------------------------------------------------------------------------
__global__ __launch_bounds__(256) void gather_kernel(
    const int* __restrict__ program, const float* __restrict__ embed,
    unsigned* __restrict__ Ag2, int total2)
{
    int idx = blockIdx.x * 256 + threadIdx.x;
    if (idx >= total2) return;
    int t = idx / 1200;
    int rem = idx - t * 1200;
    int j = rem / 150;
    int e2 = rem - j * 150;
    int tok = program[t * 8 + j];
    float2 v = *reinterpret_cast<const float2*>(&embed[(size_t)tok * 300 + e2 * 2]);
    Ag2[idx] = (unsigned)f2b(v.x) | ((unsigned)f2b(v.y) << 16);
}

// f32 -> bf16 convert, 4 elems/thread
__global__ __launch_bounds__(256) void cvt_kernel(
    const float* __restrict__ in, u16* __restrict__ out, int n4)
{
    int i = blockIdx.x * 256 + threadIdx.x;
    if (i >= n4) return;
    float4 v = reinterpret_cast<const float4*>(in)[i];
    uint2 pk;
    pk.x = (unsigned)f2b(v.x) | ((unsigned)f2b(v.y) << 16);
    pk.y = (unsigned)f2b(v.z) | ((unsigned)f2b(v.w) << 16);
    reinterpret_cast<uint2*>(out)[i] = pk;
}

// ---------------------------------------------------------------------------

extern "C" void kernel_launch(void* const* d_in, const int* in_sizes, int n_in,
                              void* d_out, int out_size, void* d_ws, size_t ws_size,
                              hipStream_t stream)
{
    const int*   program = (const int*)d_in[0];
    const int*   adj     = (const int*)d_in[1];
    const float* img     = (const float*)d_in[2];
    const float* embed   = (const float*)d_in[3];
    const float* W_in    = (const float*)d_in[4];
    const float* b_in    = (const float*)d_in[5];
    const float* ln1_g   = (const float*)d_in[6];
    const float* ln1_b   = (const float*)d_in[7];
    const float* ln2_g   = (const float*)d_in[8];
    const float* ln2_b   = (const float*)d_in[9];
    const float* Wq      = (const float*)d_in[10];
    const float* bq      = (const float*)d_in[11];
    const float* Wk      = (const float*)d_in[12];
    const float* bk      = (const float*)d_in[13];
    const float* Wv      = (const float*)d_in[14];
    const float* bv      = (const float*)d_in[15];
    const float* Wo      = (const float*)d_in[16];
    const float* bo      = (const float*)d_in[17];
    const float* fW1     = (const float*)d_in[18];
    const float* fb1     = (const float*)d_in[19];
    const float* fW2     = (const float*)d_in[20];
    const float* fb2     = (const float*)d_in[21];
    const float* cWq     = (const float*)d_in[22];
    const float* cbq     = (const float*)d_in[23];
    const float* cWk     = (const float*)d_in[24];
    const float* cbk     = (const float*)d_in[25];
    const float* cWv     = (const float*)d_in[26];
    const float* cbv     = (const float*)d_in[27];
    const float* cWo     = (const float*)d_in[28];
    const float* cbo     = (const float*)d_in[29];

    char* wsb = (char*)d_ws;
    const size_t MB = 1024 * 1024;
    const long Mi = 1048576;
    const long LSTR = 8 * Mi + Mi / 2;           // 8.5 Mi elements per layer

    float* x    = (float*)(wsb + 0);             // 4096x512 f32      (8 MB)
    u16*   h    = (u16*)(wsb + 8 * MB);          // 4096x512 bf16     (4 MB)
    u16*   xb   = (u16*)(wsb + 12 * MB);         // 4096x512 bf16     (4 MB)
    u16*   imgb = (u16*)(wsb + 16 * MB);         // 4096x512 bf16     (4 MB)
    u16*   WinT = (u16*)(wsb + 20 * MB);         // 512x2400 bf16     (2.4 MB)
    u16*   Kb   = (u16*)(wsb + 24 * MB);         // 4096x2048 bf16    (16 MB)
    u16*   Vt   = (u16*)(wsb + 40 * MB);         // [128][256][256]   (16 MB)
    u16*   O    = (u16*)(wsb + 56 * MB);         // 4096x2048 bf16    (16 MB)
    u16*   Wall = (u16*)(wsb + 72 * MB);         // transposed weights (102 MB)
    u16*   KcA  = (u16*)(wsb + 176 * MB);        // hoisted cross-K (96 MB)
    u16*   VcA  = (u16*)(wsb + 272 * MB);        // hoisted cross-V (96 MB)
    u16*   Ag   = Kb;  // gather buffer (dead before layer loop)
    u16*   g    = Kb;  // FFN mid aliases Kb (dead during FFN)

    const bool bigws = ws_size >= (size_t)175 * MB;
    const bool hoist = ws_size >= (size_t)369 * MB && bigws;

    // prologue
    gather_kernel<<<19200, 256, 0, stream>>>(program, embed, (unsigned*)Ag, 4915200);
    transpose_kernel<<<dim3(8, 19, 1), 256, 0, stream>>>(
        W_in, nullptr, nullptr, nullptr, nullptr, nullptr,
        1, 0, 2400, 512, WinT, 0, 0);
    cvt_kernel<<<2048, 256, 0, stream>>>(img, imgb, 524288);
    if (bigws) {
        transpose_kernel<<<dim3(32, 4, 36), 256, 0, stream>>>(
            Wq, Wk, Wv, cWq, cWk, cWv, 6, Mi, 512, 2048, Wall, Mi, LSTR);
        transpose_kernel<<<dim3(8, 16, 12), 256, 0, stream>>>(
            Wo, cWo, nullptr, nullptr, nullptr, nullptr,
            2, Mi, 2048, 512, Wall + 6 * Mi, Mi, LSTR);
        transpose_kernel<<<dim3(8, 4, 12), 256, 0, stream>>>(
            fW1, fW2, nullptr, nullptr, nullptr, nullptr,
            2, 262144, 512, 512, Wall + 8 * Mi, 262144, LSTR);
    }
    gemm_bf16<64, 64, 32, EPI_F32><<<dim3(8, 64, 1), 256, 0, stream>>>(
        Ag, 0, 2400, WinT, 0, 2400, 4096, 512, 2400,
        b_in, nullptr, 0, nullptr,
        x, nullptr, nullptr, 0, 512);
    if (hoist) {
        gemm_bf16<128, 128, 64, EPI_KV><<<dim3(32, 32, 6), 256, 0, stream>>>(
            imgb, 0, 512, Wall + 4 * Mi, LSTR, 512, 4096, 4096, 512,
            cbk, cbv, 2048, nullptr,
            nullptr, KcA, VcA, 8 * Mi, 2048);
    }

    for (int l = 0; l < 6; l++) {
        u16* Wl = Wall + (bigws ? (size_t)l * LSTR : 0);
        if (!bigws) {
            transpose_kernel<<<dim3(32, 4, 6), 256, 0, stream>>>(
                Wq + (size_t)l * Mi, Wk + (size_t)l * Mi, Wv + (size_t)l * Mi,
                cWq + (size_t)l * Mi, cWk + (size_t)l * Mi, cWv + (size_t)l * Mi,
                6, 0, 512, 2048, Wl, Mi, 0);
            transpose_kernel<<<dim3(8, 16, 2), 256, 0, stream>>>(
                Wo + (size_t)l * Mi, cWo + (size_t)l * Mi,
                nullptr, nullptr, nullptr, nullptr,
                2, 0, 2048, 512, Wl + 6 * Mi, Mi, 0);
            transpose_kernel<<<dim3(8, 4, 2), 256, 0, stream>>>(
                fW1 + (size_t)l * 262144, fW2 + (size_t)l * 262144,
                nullptr, nullptr, nullptr, nullptr,
                2, 0, 512, 512, Wl + 8 * Mi, 262144, 0);
        }

        // --- self-attention (Q fused into attn; KV-only GEMM) ---
        ln_kernel<<<1024, 256, 0, stream>>>(x, ln1_g + l * 512, ln1_b + l * 512, h);
        gemm_bf16<128, 128, 64, EPI_KV><<<dim3(32, 32, 1), 256, 0, stream>>>(
            h, 0, 512, Wl + 1 * Mi, 0, 512, 4096, 4096, 512,
            bk + l * 2048, bv + l * 2048, 0, nullptr,
            nullptr, Kb, Vt, 0, 2048);
        attn_kernel<true><<<dim3(8, 128), 256, 0, stream>>>(
            h, Wl, bq + l * 2048, Kb, Vt, adj, O);
        gemm_bf16<32, 64, 64, EPI_ATOMIC><<<dim3(8, 128, 2), 256, 0, stream>>>(
            O, 1024, 2048, Wl + 6 * Mi, 1024, 2048, 4096, 512, 1024,
            bo + l * 512, nullptr, 0, nullptr,
            x, nullptr, nullptr, 0, 512);

        // --- FFN ---
        ln_kernel<<<1024, 256, 0, stream>>>(x, ln2_g + l * 512, ln2_b + l * 512, h);
        gemm_bf16<32, 64, 64, EPI_GELU><<<dim3(8, 128, 1), 256, 0, stream>>>(
            h, 0, 512, Wl + 8 * Mi, 0, 512, 4096, 512, 512,
            fb1 + l * 512, nullptr, 0, nullptr,
            nullptr, g, nullptr, 0, 512);
        gemm_bf16<32, 64, 64, EPI_RESID_XB><<<dim3(8, 128, 1), 256, 0, stream>>>(
            g, 0, 512, Wl + 8 * Mi + 262144, 0, 512, 4096, 512, 512,
            fb2 + l * 512, nullptr, 0, x,
            x, xb, nullptr, 0, 512);

        // --- cross-attention (Q fused; query source = xb, no mask) ---
        u16* Kc = hoist ? (KcA + (size_t)l * 8 * Mi) : Kb;
        u16* Vc = hoist ? (VcA + (size_t)l * 8 * Mi) : Vt;
        if (!hoist) {
            gemm_bf16<128, 128, 64, EPI_KV><<<dim3(32, 32, 1), 256, 0, stream>>>(
                imgb, 0, 512, Wl + 4 * Mi, 0, 512, 4096, 4096, 512,
                cbk + l * 2048, cbv + l * 2048, 0, nullptr,
                nullptr, Kb, Vt, 0, 2048);
        }
        attn_kernel<false><<<dim3(8, 128), 256, 0, stream>>>(
            xb, Wl + 3 * Mi, cbq + l * 2048, Kc, Vc, nullptr, O);
        gemm_bf16<32, 64, 64, EPI_ATOMIC><<<dim3(8, 128, 2), 256, 0, stream>>>(
            O, 1024, 2048, Wl + 7 * Mi, 1024, 2048, 4096, 512, 1024,
            cbo + l * 512, nullptr, 0, nullptr,
            x, nullptr, nullptr, 0, 512);
    }

    hipMemcpyAsync(d_out, x, (size_t)2097152 * sizeof(float),
                   hipMemcpyDeviceToDevice, stream);
}

// Round 10
// 1341.241 us; speedup vs baseline: 1.2094x; 1.2094x over previous
//
#include <hip/hip_runtime.h>
#include <hip/hip_bf16.h>

typedef __attribute__((ext_vector_type(8))) short short8;
typedef __attribute__((ext_vector_type(4))) float f32x4;
typedef unsigned short u16;

__device__ __forceinline__ u16 f2b(float f) {
    unsigned int u = __builtin_bit_cast(unsigned int, f);
    u = u + 0x7fffu + ((u >> 16) & 1u);
    return (u16)(u >> 16);
}

// epilogue modes (template parameter)
#define EPI_F32      0   // outF = acc + bias0
#define EPI_RESID_XB 3   // outF = acc+bias0+Rsd, outB = bf16(same)
#define EPI_GELU     4   // outB = bf16(gelu(acc + bias0))
#define EPI_KV       7   // 2-way split: K(outB), V-transposed(outV); batched by bz
#define EPI_ATOMIC   9   // atomicAdd(outF, acc) (+bias0 when bz==0), split-K

// ---------------------------------------------------------------------------
// bf16 MFMA GEMM: C = A(M,K) @ Bt(N,K)^T, f32 accumulate, fused epilogue EPI.
// 2-phase double-buffered K-loop, global_load_lds width=16, source-side
// XOR swizzle, XCD-aware bijective block swizzle (needs nwg % 8 == 0).
// ---------------------------------------------------------------------------
template<int BM, int BN, int BK, int EPI>
__global__ __launch_bounds__(256, 2) void gemm_bf16(
    const u16* __restrict__ A, long aStride, int lda,
    const u16* __restrict__ B, long bStride, int ldb,
    int M, int N, int K,
    const float* __restrict__ bias0, const float* __restrict__ bias1,
    int biasStride,
    const float* __restrict__ Rsd,
    float* __restrict__ outF, u16* __restrict__ outB,
    u16* __restrict__ outV, long outStride, int ldc)
{
    constexpr int WCOLS = (BM == 32) ? 2 : (BN / 64);
    constexpr int WROWS = 4 / WCOLS;
    constexpr int WM = BM / WROWS;           // rows per wave (>=16)
    constexpr int WN = BN / WCOLS;           // cols per wave
    constexpr int MF = WM / 16;
    constexpr int NF = WN / 16;
    constexpr int GR = BK / 8;               // 16B units per row
    constexpr int AUNITS = BM * GR;
    constexpr int TOTU = (BM + BN) * GR;
    constexpr int UPT = (TOTU + 255) / 256;
    constexpr int BUFE = (BM + BN) * BK;     // u16 per LDS buffer

    __shared__ __align__(16) u16 smem[2 * BUFE];

    const int tid = threadIdx.x;
    const int wave = tid >> 6, lane = tid & 63;
    const int wm = wave / WCOLS, wn = wave % WCOLS;

    // XCD-aware bijective swizzle (chunked)
    const int nwg = gridDim.x * gridDim.y;
    const int bl = blockIdx.y * gridDim.x + blockIdx.x;
    const int wsw = (bl & 7) * (nwg >> 3) + (bl >> 3);
    const int bxs = wsw % gridDim.x, bys = wsw / gridDim.x;

    const int tm = bys * BM, tn = bxs * BN;
    const int bz = blockIdx.z;

    const size_t aOff = (size_t)bz * (size_t)aStride;
    const size_t bOff = (size_t)bz * (size_t)bStride;

    const int lr = lane & 15, kg = lane >> 4;

    auto stage = [&](int buf, int k0) {
#pragma unroll
        for (int i = 0; i < UPT; i++) {
            int u = tid + i * 256;
            if (u < TOTU) {
                u16* dst = smem + buf * BUFE + u * 8;
                bool isA = u < AUNITS;
                int v = isA ? u : u - AUNITS;
                int row, kloc;
                if constexpr (BK == 64) {
                    row = v >> 3;
                    int hh = (v >> 2) & 1, g = v & 3;
                    kloc = ((hh ^ (row & 1)) << 5) + ((g ^ ((row >> 1) & 3)) << 3);
                } else {
                    row = v >> 2;
                    int g = v & 3;
                    kloc = (g ^ ((row >> 1) & 3)) << 3;
                }
                const u16* src = isA
                    ? A + aOff + (size_t)(tm + row) * lda + k0 + kloc
                    : B + bOff + (size_t)(tn + row) * ldb + k0 + kloc;
                __builtin_amdgcn_global_load_lds(src, dst, 16, 0, 0);
            }
        }
    };

    auto ldsOff = [&](int row, int kk) -> int {
        if constexpr (BK == 64)
            return row * 64 + (((kk ^ (row & 1)) * 4 + (kg ^ ((row >> 1) & 3))) * 8);
        else
            return row * 32 + ((kg ^ ((row >> 1) & 3)) * 8);
    };

    f32x4 acc[MF][NF];
#pragma unroll
    for (int m = 0; m < MF; m++)
#pragma unroll
        for (int n = 0; n < NF; n++) acc[m][n] = (f32x4)(0.f);

    const int NT = K / BK;
    stage(0, 0);
    __syncthreads();

    for (int t = 0; t < NT; t++) {
        const int cur = t & 1;
        if (t + 1 < NT) stage(cur ^ 1, (t + 1) * BK);

        const u16* As = smem + cur * BUFE;
        const u16* Bs = As + BM * BK;
#pragma unroll
        for (int kk = 0; kk < BK / 32; kk++) {
            short8 af[MF], bfr[NF];
#pragma unroll
            for (int m = 0; m < MF; m++) {
                int row = wm * WM + m * 16 + lr;
                af[m] = *(const short8*)&As[ldsOff(row, kk)];
            }
#pragma unroll
            for (int n = 0; n < NF; n++) {
                int row = wn * WN + n * 16 + lr;
                bfr[n] = *(const short8*)&Bs[ldsOff(row, kk)];
            }
#pragma unroll
            for (int m = 0; m < MF; m++)
#pragma unroll
                for (int n = 0; n < NF; n++)
                    acc[m][n] = __builtin_amdgcn_mfma_f32_16x16x32_bf16(
                        af[m], bfr[n], acc[m][n], 0, 0, 0);
        }
        __syncthreads();   // drains prefetch (vmcnt 0) + joins waves
    }

    if constexpr (EPI == EPI_KV) {
        if (tn < 2048) {
            // ---- K half: coalesced direct stores ----
#pragma unroll
            for (int m = 0; m < MF; m++)
#pragma unroll
                for (int n = 0; n < NF; n++)
#pragma unroll
                    for (int e = 0; e < 4; e++) {
                        int r = tm + wm * WM + m * 16 + kg * 4 + e;
                        int c = tn + wn * WN + n * 16 + lr;
                        float t = acc[m][n][e] + bias0[bz * biasStride + c];
                        outB[(size_t)bz * outStride + (size_t)r * 2048 + c] = f2b(t);
                    }
        } else {
            // ---- V half: transpose via LDS, coalesced uint4 stores ----
            const int ccb = tn - 2048;             // multiple of 128
            const int bidx = tm >> 8;              // batch index
            const int hh = ccb >> 8;               // head
            u16* vls = smem;                       // [128 d][136 pad] u16
#pragma unroll
            for (int m = 0; m < MF; m++)
#pragma unroll
                for (int n = 0; n < NF; n++)
#pragma unroll
                    for (int e = 0; e < 4; e++) {
                        int rl = wm * WM + m * 16 + kg * 4 + e;   // local tok
                        int cl = wn * WN + n * 16 + lr;           // local d
                        float t = acc[m][n][e] + bias1[bz * biasStride + ccb + cl];
                        vls[cl * 136 + rl] = f2b(t);
                    }
            __syncthreads();
            const int dloc = tid >> 1;
            const int thalf = (tid & 1) * 64;
            const int dglob = (ccb & 255) + dloc;
            u16* dst = outV + (size_t)bz * outStride +
                       (size_t)(bidx * 8 + hh) * 65536 +
                       (size_t)dglob * 256 + (tm & 255) + thalf;
            const u16* srcl = vls + dloc * 136 + thalf;
#pragma unroll
            for (int k = 0; k < 8; k++)
                *(uint4*)(dst + k * 8) = *(const uint4*)(srcl + k * 8);
        }
        return;
    }

    // generic epilogue: D row=(lane>>4)*4+e, col=lane&15
#pragma unroll
    for (int m = 0; m < MF; m++) {
#pragma unroll
        for (int n = 0; n < NF; n++) {
#pragma unroll
            for (int e = 0; e < 4; e++) {
                int r = tm + wm * WM + m * 16 + (lane >> 4) * 4 + e;
                int c = tn + wn * WN + n * 16 + (lane & 15);
                float v = acc[m][n][e];
                if constexpr (EPI == EPI_F32) {
                    outF[(size_t)r * ldc + c] = v + bias0[c];
                } else if constexpr (EPI == EPI_RESID_XB) {
                    float t = v + bias0[c] + Rsd[(size_t)r * ldc + c];
                    outF[(size_t)r * ldc + c] = t;
                    outB[(size_t)r * ldc + c] = f2b(t);
                } else if constexpr (EPI == EPI_GELU) {
                    float t = v + bias0[c];
                    t = 0.5f * t * (1.f + erff(t * 0.70710678118654752f));
                    outB[(size_t)r * ldc + c] = f2b(t);
                } else if constexpr (EPI == EPI_ATOMIC) {
                    float t = v;
                    if (bz == 0) t += bias0[c];
                    atomicAdd(&outF[(size_t)r * ldc + c], t);
                }
            }
        }
    }
}

// ---------------------------------------------------------------------------
// Fused attention with Q-projection, QBLK=64 (grid 4 x 128, 2 blocks/CU).
// Phase 0 (Q-proj) barrier'd; phases 1 (QK^T) and 4 (PV) use WAVE-PRIVATE
// K/V staging: wave w stages exactly the 64 rows it consumes, synchronized
// with per-wave counted s_waitcnt vmcnt(N) instead of __syncthreads.
// ---------------------------------------------------------------------------
template<bool MASKED>
__global__ __launch_bounds__(256, 2) void attn_kernel(
    const u16* __restrict__ Aq, const u16* __restrict__ WqT,
    const float* __restrict__ bq,
    const u16* __restrict__ K, const u16* __restrict__ Vt,
    const int* __restrict__ adj, u16* __restrict__ O)
{
    __shared__ __align__(16) u16 Ps[64 * 256];       // Q tile then P tile (32 KB)
    __shared__ __align__(16) u16 Ks[2 * 256 * 32];   // B double buffer (32 KB)
    __shared__ __align__(16) u16 Aql[2 * 64 * 32];   // phase-0 A dbuf (8 KB)
    __shared__ float red1[64 * 4];
    __shared__ float red2[64 * 4];

    const int tid = threadIdx.x;
    const int w = tid >> 6, lane = tid & 63;
    const int lr = lane & 15, kg = lane >> 4;

    // XCD swizzle: 4 qt-blocks of a bh colocate
    const int nwg = gridDim.x * gridDim.y;
    const int bl = blockIdx.y * gridDim.x + blockIdx.x;
    const int wsw = (bl & 7) * (nwg >> 3) + (bl >> 3);
    const int qt = wsw % gridDim.x, bh = wsw / gridDim.x;

    const int b = bh >> 3, h = bh & 7;
    const size_t qkBase = (size_t)b * 256 * 2048 + h * 256;

    auto stageA0 = [&](int buf, int k0) {
        int u = tid;                       // 256 units exactly (shared A tile)
        int row = u >> 2, g = u & 3;
        int gs = g ^ ((row >> 1) & 3);
        const u16* src = Aq + (size_t)(b * 256 + qt * 64 + row) * 512 + k0 + gs * 8;
        __builtin_amdgcn_global_load_lds(src, Aql + buf * 2048 + u * 8, 16, 0, 0);
    };
    auto stageB0 = [&](int buf, int k0) {
#pragma unroll
        for (int i = 0; i < 4; i++) {
            int u = tid + i * 256;
            int row = u >> 2, g = u & 3;
            int gs = g ^ ((row >> 1) & 3);
            const u16* src = WqT + (size_t)(h * 256 + row) * 512 + k0 + gs * 8;
            __builtin_amdgcn_global_load_lds(src, Ks + buf * 8192 + u * 8, 16, 0, 0);
        }
    };
    // wave-private: wave w stages its own rows w*64..w*64+63 (same LDS layout)
    auto stageK = [&](int buf, int dk) {
#pragma unroll
        for (int i = 0; i < 4; i++) {
            int u = w * 256 + i * 64 + lane;
            int row = u >> 2, g = u & 3;
            int gs = g ^ ((row >> 1) & 3);
            const u16* src = K + qkBase + (size_t)row * 2048 + dk * 32 + gs * 8;
            __builtin_amdgcn_global_load_lds(src, Ks + buf * 8192 + u * 8, 16, 0, 0);
        }
    };
    auto stageV = [&](int buf, int kt) {
#pragma unroll
        for (int i = 0; i < 4; i++) {
            int u = w * 256 + i * 64 + lane;
            int row = u >> 2, g = u & 3;   // row = d
            int gs = g ^ ((row >> 1) & 3);
            const u16* src = Vt + (size_t)bh * 65536 + (size_t)row * 256 + kt * 32 + gs * 8;
            __builtin_amdgcn_global_load_lds(src, Ks + buf * 8192 + u * 8, 16, 0, 0);
        }
    };

    // ---- phase 0: Q = Aq @ WqT_head + bq  (K=512, 16 steps of 32) ----
    {
        f32x4 qacc[4][4];
#pragma unroll
        for (int m = 0; m < 4; m++)
#pragma unroll
            for (int n = 0; n < 4; n++) qacc[m][n] = (f32x4)(0.f);

        stageA0(0, 0);
        stageB0(0, 0);
        __syncthreads();
        for (int t = 0; t < 16; t++) {
            const int cur = t & 1;
            if (t < 15) { stageA0(cur ^ 1, (t + 1) * 32); stageB0(cur ^ 1, (t + 1) * 32); }
            short8 af[4], bfr[4];
#pragma unroll
            for (int m = 0; m < 4; m++) {
                int row = m * 16 + lr;
                af[m] = *(const short8*)&Aql[cur * 2048 + row * 32 + ((kg ^ ((row >> 1) & 3)) * 8)];
            }
#pragma unroll
            for (int n = 0; n < 4; n++) {
                int row = w * 64 + n * 16 + lr;
                bfr[n] = *(const short8*)&Ks[cur * 8192 + row * 32 + ((kg ^ ((row >> 1) & 3)) * 8)];
            }
            __builtin_amdgcn_s_setprio(1);
#pragma unroll
            for (int m = 0; m < 4; m++)
#pragma unroll
                for (int n = 0; n < 4; n++)
                    qacc[m][n] = __builtin_amdgcn_mfma_f32_16x16x32_bf16(
                        af[m], bfr[n], qacc[m][n], 0, 0, 0);
            __builtin_amdgcn_s_setprio(0);
            __syncthreads();
        }
        // issue K tile 0 (wave-private) early: overlaps Q-write
        stageK(0, 0);
        // write Q tile to Ps (bf16, swizzled for phase-1 A reads)
#pragma unroll
        for (int m = 0; m < 4; m++)
#pragma unroll
            for (int n = 0; n < 4; n++)
#pragma unroll
                for (int e = 0; e < 4; e++) {
                    int q = m * 16 + kg * 4 + e;
                    int d = w * 64 + n * 16 + lr;
                    float t = qacc[m][n][e] + bq[h * 256 + d];
                    Ps[q * 256 + (((d >> 3) ^ (q & 7)) * 8) + (d & 7)] = f2b(t);
                }
    }
    __syncthreads();   // Ps visible; K tile 0 drained (full vmcnt drain)

    f32x4 sacc[4][4];
#pragma unroll
    for (int m = 0; m < 4; m++)
#pragma unroll
        for (int n = 0; n < 4; n++) sacc[m][n] = (f32x4)(0.f);

    // ---- phase 1: S = Q K^T (8 steps of 32) -- wave-private, barrier-free
    for (int dk = 0; dk < 8; dk++) {
        const int cur = dk & 1;
        if (dk < 7) {
            stageK(cur ^ 1, dk + 1);
            asm volatile("s_waitcnt vmcnt(4)" ::: "memory");
        } else {
            asm volatile("s_waitcnt vmcnt(0)" ::: "memory");
        }
        __builtin_amdgcn_sched_barrier(0);
        short8 af[4], bfr[4];
#pragma unroll
        for (int m = 0; m < 4; m++) {
            int row = m * 16 + lr;
            af[m] = *(const short8*)&Ps[row * 256 + (((dk * 4 + kg) ^ (row & 7)) * 8)];
        }
#pragma unroll
        for (int n = 0; n < 4; n++) {
            int row = w * 64 + n * 16 + lr;
            bfr[n] = *(const short8*)&Ks[cur * 8192 + row * 32 + ((kg ^ ((row >> 1) & 3)) * 8)];
        }
        __builtin_amdgcn_s_setprio(1);
#pragma unroll
        for (int m = 0; m < 4; m++)
#pragma unroll
            for (int n = 0; n < 4; n++)
                sacc[m][n] = __builtin_amdgcn_mfma_f32_16x16x32_bf16(
                    af[m], bfr[n], sacc[m][n], 0, 0, 0);
        __builtin_amdgcn_s_setprio(0);
    }

    // prefetch V tile 0 (wave-private; drained by softmax barriers)
    stageV(0, 0);

    // ---- phase 2: scale + mask + softmax(+1 denom) ----
#pragma unroll
    for (int m = 0; m < 4; m++)
#pragma unroll
        for (int n = 0; n < 4; n++)
#pragma unroll
            for (int e = 0; e < 4; e++) {
                float t = sacc[m][n][e] * 0.0625f;
                if (MASKED) {
                    int q = qt * 64 + m * 16 + kg * 4 + e;
                    int k = w * 64 + n * 16 + lr;
                    int a_ = adj[((size_t)b * 256 + q) * 256 + k];
                    t += (1.f - (float)a_) * -1.0e6f;
                }
                sacc[m][n][e] = t;
            }

    float mx[4][4];
#pragma unroll
    for (int m = 0; m < 4; m++)
#pragma unroll
        for (int e = 0; e < 4; e++) {
            float v = sacc[m][0][e];
#pragma unroll
            for (int n = 1; n < 4; n++) v = fmaxf(v, sacc[m][n][e]);
#pragma unroll
            for (int off = 1; off < 16; off <<= 1) v = fmaxf(v, __shfl_xor(v, off));
            mx[m][e] = v;
        }
    if (lr == 0) {
#pragma unroll
        for (int m = 0; m < 4; m++)
#pragma unroll
            for (int e = 0; e < 4; e++)
                red1[(m * 16 + kg * 4 + e) * 4 + w] = mx[m][e];
    }
    __syncthreads();

    float inv[4][4];
    float sum[4][4];
#pragma unroll
    for (int m = 0; m < 4; m++)
#pragma unroll
        for (int e = 0; e < 4; e++) {
            int r = m * 16 + kg * 4 + e;
            float gm = fmaxf(fmaxf(red1[r * 4 + 0], red1[r * 4 + 1]),
                             fmaxf(red1[r * 4 + 2], red1[r * 4 + 3]));
            float s = 0.f;
#pragma unroll
            for (int n = 0; n < 4; n++) {
                float ev = __expf(sacc[m][n][e] - gm);
                sacc[m][n][e] = ev;
                s += ev;
            }
            sum[m][e] = s;
        }
#pragma unroll
    for (int m = 0; m < 4; m++)
#pragma unroll
        for (int e = 0; e < 4; e++) {
            float s = sum[m][e];
#pragma unroll
            for (int off = 1; off < 16; off <<= 1) s += __shfl_xor(s, off);
            sum[m][e] = s;
        }
    if (lr == 0) {
#pragma unroll
        for (int m = 0; m < 4; m++)
#pragma unroll
            for (int e = 0; e < 4; e++)
                red2[(m * 16 + kg * 4 + e) * 4 + w] = sum[m][e];
    }
    __syncthreads();
#pragma unroll
    for (int m = 0; m < 4; m++)
#pragma unroll
        for (int e = 0; e < 4; e++) {
            int r = m * 16 + kg * 4 + e;
            float gs = red2[r * 4 + 0] + red2[r * 4 + 1] +
                       red2[r * 4 + 2] + red2[r * 4 + 3];
            inv[m][e] = 1.f / (1.f + gs);
        }

    // ---- phase 3: P -> LDS (bf16, overwrites Q tile) ----
#pragma unroll
    for (int m = 0; m < 4; m++)
#pragma unroll
        for (int n = 0; n < 4; n++)
#pragma unroll
            for (int e = 0; e < 4; e++) {
                int q = m * 16 + kg * 4 + e;
                int k = w * 64 + n * 16 + lr;
                float pv = sacc[m][n][e] * inv[m][e];
                Ps[q * 256 + (((k >> 3) ^ (q & 7)) * 8) + (k & 7)] = f2b(pv);
            }
    __syncthreads();   // P visible; V tile 0 drained

    // ---- phase 4: O = P V (8 steps of 32) -- wave-private, barrier-free
    f32x4 oacc[4][4];
#pragma unroll
    for (int m = 0; m < 4; m++)
#pragma unroll
        for (int n = 0; n < 4; n++) oacc[m][n] = (f32x4)(0.f);

    for (int kt = 0; kt < 8; kt++) {
        const int cur = kt & 1;
        if (kt < 7) {
            stageV(cur ^ 1, kt + 1);
            asm volatile("s_waitcnt vmcnt(4)" ::: "memory");
        } else {
            asm volatile("s_waitcnt vmcnt(0)" ::: "memory");
        }
        __builtin_amdgcn_sched_barrier(0);
        short8 af[4], bfr[4];
#pragma unroll
        for (int m = 0; m < 4; m++) {
            int q = m * 16 + lr;
            af[m] = *(const short8*)&Ps[q * 256 + (((kt * 4 + kg) ^ (q & 7)) * 8)];
        }
#pragma unroll
        for (int n = 0; n < 4; n++) {
            int row = w * 64 + n * 16 + lr;
            bfr[n] = *(const short8*)&Ks[cur * 8192 + row * 32 + ((kg ^ ((row >> 1) & 3)) * 8)];
        }
        __builtin_amdgcn_s_setprio(1);
#pragma unroll
        for (int m = 0; m < 4; m++)
#pragma unroll
            for (int n = 0; n < 4; n++)
                oacc[m][n] = __builtin_amdgcn_mfma_f32_16x16x32_bf16(
                    af[m], bfr[n], oacc[m][n], 0, 0, 0);
        __builtin_amdgcn_s_setprio(0);
    }

    // ---- epilogue: O[tok][h*256+d] ----
#pragma unroll
    for (int m = 0; m < 4; m++)
#pragma unroll
        for (int n = 0; n < 4; n++)
#pragma unroll
            for (int e = 0; e < 4; e++) {
                int q = qt * 64 + m * 16 + kg * 4 + e;
                int d = w * 64 + n * 16 + lr;
                O[(size_t)(b * 256 + q) * 2048 + h * 256 + d] = f2b(oacc[m][n][e]);
            }
}

// ---------------------------------------------------------------------------
// Transpose+convert: src f32 [R][C] -> dst bf16 [C][R].
// float4 global loads, [64][65] LDS (2-way = free), uint2 stores.
// ---------------------------------------------------------------------------
__global__ __launch_bounds__(256) void transpose_kernel(
    const float* p0, const float* p1, const float* p2,
    const float* p3, const float* p4, const float* p5,
    int nsrc, long srcLayerStride, int R, int C,
    u16* __restrict__ out, long dstMatStride, long dstLayerStride)
{
    const int mat = blockIdx.z % nsrc, layer = blockIdx.z / nsrc;
    const float* W;
    switch (mat) {
    default: W = p0; break;
    case 1: W = p1; break;
    case 2: W = p2; break;
    case 3: W = p3; break;
    case 4: W = p4; break;
    case 5: W = p5; break;
    }
    W += (size_t)layer * srcLayerStride;
    u16* o = out + (size_t)layer * dstLayerStride + (size_t)mat * dstMatStride;
    __shared__ float t[64][65];
    const int tid = threadIdx.x;
    const int rBase = blockIdx.y * 64, cBase = blockIdx.x * 64;
#pragma unroll
    for (int i = 0; i < 4; i++) {
        int idx = tid + i * 256;
        int rr = idx >> 4, cc4 = (idx & 15) * 4;
        if (rBase + rr < R) {
            float4 v = *(const float4*)&W[(size_t)(rBase + rr) * C + cBase + cc4];
            t[rr][cc4] = v.x; t[rr][cc4 + 1] = v.y;
            t[rr][cc4 + 2] = v.z; t[rr][cc4 + 3] = v.w;
        }
    }
    __syncthreads();
#pragma unroll
    for (int i = 0; i < 4; i++) {
        int idx = tid + i * 256;
        int cc = idx >> 4, rr4 = (idx & 15) * 4;
        if (rBase + rr4 < R) {
            uint2 pk;
            pk.x = (unsigned)f2b(t[rr4][cc]) | ((unsigned)f2b(t[rr4 + 1][cc]) << 16);
            pk.y = (unsigned)f2b(t[rr4 + 2][cc]) | ((unsigned)f2b(t[rr4 + 3][cc]) << 16);
            *(uint2*)&o[(size_t)(cBase + cc) * R + rBase + rr4] = pk;
        }
    }
}

// ---------------------------------------------------------------------------
// LayerNorm rows of 512, f32 in -> bf16 out. One wave per row.
// ---------------------------------------------------------------------------
__global__ __launch_bounds__(256) void ln_kernel(
    const float* __restrict__ X, const float* __restrict__ g,
    const float* __restrict__ b, u16* __restrict__ Y)
{
    const int wave = threadIdx.x >> 6, lane = threadIdx.x & 63;
    const size_t row = (size_t)blockIdx.x * 4 + wave;
    const float* xr = X + row * 512;
    float4 v0 = *reinterpret_cast<const float4*>(xr + lane * 8);
    float4 v1 = *reinterpret_cast<const float4*>(xr + lane * 8 + 4);
    float s = v0.x + v0.y + v0.z + v0.w + v1.x + v1.y + v1.z + v1.w;
    float ss = v0.x * v0.x + v0.y * v0.y + v0.z * v0.z + v0.w * v0.w +
               v1.x * v1.x + v1.y * v1.y + v1.z * v1.z + v1.w * v1.w;
#pragma unroll
    for (int off = 32; off; off >>= 1) {
        s += __shfl_xor(s, off);
        ss += __shfl_xor(ss, off);
    }
    float mu = s * (1.0f / 512.0f);
    float var = ss * (1.0f / 512.0f) - mu * mu;
    float rs = rsqrtf(var + 1e-5f);
    float4 g0 = *reinterpret_cast<const float4*>(g + lane * 8);
    float4 g1 = *reinterpret_cast<const float4*>(g + lane * 8 + 4);
    float4 b0 = *reinterpret_cast<const float4*>(b + lane * 8);
    float4 b1 = *reinterpret_cast<const float4*>(b + lane * 8 + 4);
    float o0 = (v0.x - mu) * rs * g0.x + b0.x;
    float o1 = (v0.y - mu) * rs * g0.y + b0.y;
    float o2 = (v0.z - mu) * rs * g0.z + b0.z;
    float o3 = (v0.w - mu) * rs * g0.w + b0.w;
    float o4 = (v1.x - mu) * rs * g1.x + b1.x;
    float o5 = (v1.y - mu) * rs * g1.y + b1.y;
    float o6 = (v1.z - mu) * rs * g1.z + b1.z;
    float o7 = (v1.w - mu) * rs * g1.w + b1.w;
    uint4 pk;
    pk.x = (unsigned)f2b(o0) | ((unsigned)f2b(o1) << 16);
    pk.y = (unsigned)f2b(o2) | ((unsigned)f2b(o3) << 16);
    pk.z = (unsigned)f2b(o4) | ((unsigned)f2b(o5) << 16);
    pk.w = (unsigned)f2b(o6) | ((unsigned)f2b(o7) << 16);
    *reinterpret_cast<uint4*>(Y + row * 512 + lane * 8) = pk;
}

// ---------------------------------------------------------------------------
// Embedding gather -> bf16 (2 elems/thread)
// ---------------------------------------------------------------------------
__global__ __launch_bounds__(256) void gather_kernel(
    const int* __restrict__ program, const float* __restrict__ embed,
    unsigned* __restrict__ Ag2, int total2)
{
    int idx = blockIdx.x * 256 + threadIdx.x;
    if (idx >= total2) return;
    int t = idx / 1200;
    int rem = idx - t * 1200;
    int j = rem / 150;
    int e2 = rem - j * 150;
    int tok = program[t * 8 + j];
    float2 v = *reinterpret_cast<const float2*>(&embed[(size_t)tok * 300 + e2 * 2]);
    Ag2[idx] = (unsigned)f2b(v.x) | ((unsigned)f2b(v.y) << 16);
}

// f32 -> bf16 convert, 4 elems/thread
__global__ __launch_bounds__(256) void cvt_kernel(
    const float* __restrict__ in, u16* __restrict__ out, int n4)
{
    int i = blockIdx.x * 256 + threadIdx.x;
    if (i >= n4) return;
    float4 v = reinterpret_cast<const float4*>(in)[i];
    uint2 pk;
    pk.x = (unsigned)f2b(v.x) | ((unsigned)f2b(v.y) << 16);
    pk.y = (unsigned)f2b(v.z) | ((unsigned)f2b(v.w) << 16);
    reinterpret_cast<uint2*>(out)[i] = pk;
}

// ---------------------------------------------------------------------------

extern "C" void kernel_launch(void* const* d_in, const int* in_sizes, int n_in,
                              void* d_out, int out_size, void* d_ws, size_t ws_size,
                              hipStream_t stream)
{
    const int*   program = (const int*)d_in[0];
    const int*   adj     = (const int*)d_in[1];
    const float* img     = (const float*)d_in[2];
    const float* embed   = (const float*)d_in[3];
    const float* W_in    = (const float*)d_in[4];
    const float* b_in    = (const float*)d_in[5];
    const float* ln1_g   = (const float*)d_in[6];
    const float* ln1_b   = (const float*)d_in[7];
    const float* ln2_g   = (const float*)d_in[8];
    const float* ln2_b   = (const float*)d_in[9];
    const float* Wq      = (const float*)d_in[10];
    const float* bq      = (const float*)d_in[11];
    const float* Wk      = (const float*)d_in[12];
    const float* bk      = (const float*)d_in[13];
    const float* Wv      = (const float*)d_in[14];
    const float* bv      = (const float*)d_in[15];
    const float* Wo      = (const float*)d_in[16];
    const float* bo      = (const float*)d_in[17];
    const float* fW1     = (const float*)d_in[18];
    const float* fb1     = (const float*)d_in[19];
    const float* fW2     = (const float*)d_in[20];
    const float* fb2     = (const float*)d_in[21];
    const float* cWq     = (const float*)d_in[22];
    const float* cbq     = (const float*)d_in[23];
    const float* cWk     = (const float*)d_in[24];
    const float* cbk     = (const float*)d_in[25];
    const float* cWv     = (const float*)d_in[26];
    const float* cbv     = (const float*)d_in[27];
    const float* cWo     = (const float*)d_in[28];
    const float* cbo     = (const float*)d_in[29];

    char* wsb = (char*)d_ws;
    const size_t MB = 1024 * 1024;
    const long Mi = 1048576;
    const long LSTR = 8 * Mi + Mi / 2;           // 8.5 Mi elements per layer

    float* x    = (float*)(wsb + 0);             // 4096x512 f32      (8 MB)
    u16*   h    = (u16*)(wsb + 8 * MB);          // 4096x512 bf16     (4 MB)
    u16*   xb   = (u16*)(wsb + 12 * MB);         // 4096x512 bf16     (4 MB)
    u16*   imgb = (u16*)(wsb + 16 * MB);         // 4096x512 bf16     (4 MB)
    u16*   WinT = (u16*)(wsb + 20 * MB);         // 512x2400 bf16     (2.4 MB)
    u16*   Kb   = (u16*)(wsb + 24 * MB);         // 4096x2048 bf16    (16 MB)
    u16*   Vt   = (u16*)(wsb + 40 * MB);         // [128][256][256]   (16 MB)
    u16*   O    = (u16*)(wsb + 56 * MB);         // 4096x2048 bf16    (16 MB)
    u16*   Wall = (u16*)(wsb + 72 * MB);         // transposed weights (102 MB)
    u16*   KcA  = (u16*)(wsb + 176 * MB);        // hoisted cross-K (96 MB)
    u16*   VcA  = (u16*)(wsb + 272 * MB);        // hoisted cross-V (96 MB)
    u16*   Ag   = Kb;  // gather buffer (dead before layer loop)
    u16*   g    = Kb;  // FFN mid aliases Kb (dead during FFN)

    const bool bigws = ws_size >= (size_t)175 * MB;
    const bool hoist = ws_size >= (size_t)369 * MB && bigws;

    // prologue
    gather_kernel<<<19200, 256, 0, stream>>>(program, embed, (unsigned*)Ag, 4915200);
    transpose_kernel<<<dim3(8, 38, 1), 256, 0, stream>>>(
        W_in, nullptr, nullptr, nullptr, nullptr, nullptr,
        1, 0, 2400, 512, WinT, 0, 0);
    cvt_kernel<<<2048, 256, 0, stream>>>(img, imgb, 524288);
    if (bigws) {
        transpose_kernel<<<dim3(32, 8, 36), 256, 0, stream>>>(
            Wq, Wk, Wv, cWq, cWk, cWv, 6, Mi, 512, 2048, Wall, Mi, LSTR);
        transpose_kernel<<<dim3(8, 32, 12), 256, 0, stream>>>(
            Wo, cWo, nullptr, nullptr, nullptr, nullptr,
            2, Mi, 2048, 512, Wall + 6 * Mi, Mi, LSTR);
        transpose_kernel<<<dim3(8, 8, 12), 256, 0, stream>>>(
            fW1, fW2, nullptr, nullptr, nullptr, nullptr,
            2, 262144, 512, 512, Wall + 8 * Mi, 262144, LSTR);
    }
    gemm_bf16<64, 64, 32, EPI_F32><<<dim3(8, 64, 1), 256, 0, stream>>>(
        Ag, 0, 2400, WinT, 0, 2400, 4096, 512, 2400,
        b_in, nullptr, 0, nullptr,
        x, nullptr, nullptr, 0, 512);
    if (hoist) {
        gemm_bf16<128, 128, 64, EPI_KV><<<dim3(32, 32, 6), 256, 0, stream>>>(
            imgb, 0, 512, Wall + 4 * Mi, LSTR, 512, 4096, 4096, 512,
            cbk, cbv, 2048, nullptr,
            nullptr, KcA, VcA, 8 * Mi, 2048);
    }

    for (int l = 0; l < 6; l++) {
        u16* Wl = Wall + (bigws ? (size_t)l * LSTR : 0);
        if (!bigws) {
            transpose_kernel<<<dim3(32, 8, 6), 256, 0, stream>>>(
                Wq + (size_t)l * Mi, Wk + (size_t)l * Mi, Wv + (size_t)l * Mi,
                cWq + (size_t)l * Mi, cWk + (size_t)l * Mi, cWv + (size_t)l * Mi,
                6, 0, 512, 2048, Wl, Mi, 0);
            transpose_kernel<<<dim3(8, 32, 2), 256, 0, stream>>>(
                Wo + (size_t)l * Mi, cWo + (size_t)l * Mi,
                nullptr, nullptr, nullptr, nullptr,
                2, 0, 2048, 512, Wl + 6 * Mi, Mi, 0);
            transpose_kernel<<<dim3(8, 8, 2), 256, 0, stream>>>(
                fW1 + (size_t)l * 262144, fW2 + (size_t)l * 262144,
                nullptr, nullptr, nullptr, nullptr,
                2, 0, 512, 512, Wl + 8 * Mi, 262144, 0);
        }

        // --- self-attention (Q fused into attn; KV-only GEMM) ---
        ln_kernel<<<1024, 256, 0, stream>>>(x, ln1_g + l * 512, ln1_b + l * 512, h);
        gemm_bf16<128, 128, 64, EPI_KV><<<dim3(32, 32, 1), 256, 0, stream>>>(
            h, 0, 512, Wl + 1 * Mi, 0, 512, 4096, 4096, 512,
            bk + l * 2048, bv + l * 2048, 0, nullptr,
            nullptr, Kb, Vt, 0, 2048);
        attn_kernel<true><<<dim3(4, 128), 256, 0, stream>>>(
            h, Wl, bq + l * 2048, Kb, Vt, adj, O);
        gemm_bf16<64, 64, 64, EPI_ATOMIC><<<dim3(8, 64, 2), 256, 0, stream>>>(
            O, 1024, 2048, Wl + 6 * Mi, 1024, 2048, 4096, 512, 1024,
            bo + l * 512, nullptr, 0, nullptr,
            x, nullptr, nullptr, 0, 512);

        // --- FFN ---
        ln_kernel<<<1024, 256, 0, stream>>>(x, ln2_g + l * 512, ln2_b + l * 512, h);
        gemm_bf16<64, 64, 64, EPI_GELU><<<dim3(8, 64, 1), 256, 0, stream>>>(
            h, 0, 512, Wl + 8 * Mi, 0, 512, 4096, 512, 512,
            fb1 + l * 512, nullptr, 0, nullptr,
            nullptr, g, nullptr, 0, 512);
        gemm_bf16<64, 64, 64, EPI_RESID_XB><<<dim3(8, 64, 1), 256, 0, stream>>>(
            g, 0, 512, Wl + 8 * Mi + 262144, 0, 512, 4096, 512, 512,
            fb2 + l * 512, nullptr, 0, x,
            x, xb, nullptr, 0, 512);

        // --- cross-attention (Q fused; query source = xb, no mask) ---
        u16* Kc = hoist ? (KcA + (size_t)l * 8 * Mi) : Kb;
        u16* Vc = hoist ? (VcA + (size_t)l * 8 * Mi) : Vt;
        if (!hoist) {
            gemm_bf16<128, 128, 64, EPI_KV><<<dim3(32, 32, 1), 256, 0, stream>>>(
                imgb, 0, 512, Wl + 4 * Mi, 0, 512, 4096, 4096, 512,
                cbk + l * 2048, cbv + l * 2048, 0, nullptr,
                nullptr, Kb, Vt, 0, 2048);
        }
        attn_kernel<false><<<dim3(4, 128), 256, 0, stream>>>(
            xb, Wl + 3 * Mi, cbq + l * 2048, Kc, Vc, nullptr, O);
        gemm_bf16<64, 64, 64, EPI_ATOMIC><<<dim3(8, 64, 2), 256, 0, stream>>>(
            O, 1024, 2048, Wl + 7 * Mi, 1024, 2048, 4096, 512, 1024,
            cbo + l * 512, nullptr, 0, nullptr,
            x, nullptr, nullptr, 0, 512);
    }

    hipMemcpyAsync(d_out, x, (size_t)2097152 * sizeof(float),
                   hipMemcpyDeviceToDevice, stream);
}